// Round 8
// baseline (1147.705 us; speedup 1.0000x reference)
//
#include <hip/hip_runtime.h>

#define N_NODES 100000
#define N_EDGES 1600000
#define DIM_IN  256
#define DIM_HID 128
#define DIM_OUT 64

#define BM 128
#define BN 64
#define BK 32
#define GXM ((N_NODES + BM - 1) / BM)   // 782 M-tiles

// ---------------- GEMM tile 128x64 (F=64 outputs; 52 VGPR, fits (256,4)) -----
__device__ __forceinline__ void gemm_tile(
    int bx, int by,
    const float* __restrict__ A, const float* __restrict__ W,
    const float* __restrict__ bias, float* __restrict__ C,
    int M, int K, int F, int do_relu,
    float (*As)[BM], float (*Ws)[BN])
{
    const int tid = threadIdx.x;
    const int tx = tid & 15;        // n: 4 cols each
    const int ty = tid >> 4;        // m: 8 rows each
    const int bm = bx * BM;
    const int bn = by * BN;

    const int am  = tid >> 3;       // A staging: row 0..31 (+32*it)
    const int akq = tid & 7;        // A staging: float4 index within 32-k row
    const int wr  = tid >> 4;       // W staging: row 0..15 (+16*it)
    const int wcq = tid & 15;       // W staging: float4 col

    float acc[8][4] = {};

    for (int k0 = 0; k0 < K; k0 += BK) {
        #pragma unroll
        for (int it = 0; it < 4; ++it) {
            int m = am + it * 32;
            int gm = bm + m;
            float4 a4 = make_float4(0.f, 0.f, 0.f, 0.f);
            if (gm < M)
                a4 = *(const float4*)&A[(size_t)gm * K + k0 + akq * 4];
            int msw = m ^ (akq << 3);
            As[akq * 4 + 0][msw] = a4.x;
            As[akq * 4 + 1][msw] = a4.y;
            As[akq * 4 + 2][msw] = a4.z;
            As[akq * 4 + 3][msw] = a4.w;
        }
        #pragma unroll
        for (int it = 0; it < 2; ++it) {
            int r = wr + it * 16;
            float4 w4 = *(const float4*)&W[(size_t)(k0 + r) * F + bn + wcq * 4];
            *(float4*)&Ws[r][wcq * 4] = w4;
        }
        __syncthreads();
        #pragma unroll
        for (int kk = 0; kk < BK; ++kk) {
            const float* ap = &As[kk][(ty * 8) ^ (((kk >> 2) & 7) << 3)];
            float4 a0 = *(const float4*)(ap);
            float4 a1 = *(const float4*)(ap + 4);
            float4 w4 = *(const float4*)&Ws[kk][tx * 4];
            float a[8] = {a0.x, a0.y, a0.z, a0.w, a1.x, a1.y, a1.z, a1.w};
            float w[4] = {w4.x, w4.y, w4.z, w4.w};
            #pragma unroll
            for (int i = 0; i < 8; ++i)
                #pragma unroll
                for (int j = 0; j < 4; ++j)
                    acc[i][j] = fmaf(a[i], w[j], acc[i][j]);
        }
        __syncthreads();
    }
    float4 b4 = *(const float4*)&bias[bn + tx * 4];
    #pragma unroll
    for (int i = 0; i < 8; ++i) {
        int m = bm + ty * 8 + i;
        if (m < M) {
            float4 v;
            v.x = acc[i][0] + b4.x;
            v.y = acc[i][1] + b4.y;
            v.z = acc[i][2] + b4.z;
            v.w = acc[i][3] + b4.w;
            if (do_relu) {
                v.x = fmaxf(v.x, 0.f); v.y = fmaxf(v.y, 0.f);
                v.z = fmaxf(v.z, 0.f); v.w = fmaxf(v.w, 0.f);
            }
            *(float4*)&C[(size_t)m * F + bn + tx * 4] = v;
        }
    }
}

// ---------------- GEMM tile 128x128 (F=128 outputs; needs ~115 VGPR) ---------
// MUST live in a __launch_bounds__(256,2) kernel: (256,4) caps VGPR at 64 and
// spills the 64-reg accumulator to scratch (round-5 regression, WRITE +190MB).
__device__ __forceinline__ void gemm_tile128(
    int bx, int by,
    const float* __restrict__ A, const float* __restrict__ W,
    const float* __restrict__ bias, float* __restrict__ C,
    int M, int K, int F, int do_relu,
    float (*As)[BM], float (*Ws)[128])
{
    const int tid = threadIdx.x;
    const int tx = tid & 15;        // 16 col-groups of 8
    const int ty = tid >> 4;        // 16 row-groups of 8
    const int bm = bx * BM;
    const int bn = by * 128;

    const int am  = tid >> 3;       // A staging: row 0..31 (+32*it)
    const int akq = tid & 7;        // A staging: float4 index
    const int wr8 = tid >> 5;       // W staging: row 0..7 (+8*it)
    const int wcq = tid & 31;       // W staging: float4 col 0..31

    float acc[8][8] = {};

    for (int k0 = 0; k0 < K; k0 += BK) {
        #pragma unroll
        for (int it = 0; it < 4; ++it) {
            int m = am + it * 32;
            int gm = bm + m;
            float4 a4 = make_float4(0.f, 0.f, 0.f, 0.f);
            if (gm < M)
                a4 = *(const float4*)&A[(size_t)gm * K + k0 + akq * 4];
            int msw = m ^ (akq << 3);
            As[akq * 4 + 0][msw] = a4.x;
            As[akq * 4 + 1][msw] = a4.y;
            As[akq * 4 + 2][msw] = a4.z;
            As[akq * 4 + 3][msw] = a4.w;
        }
        #pragma unroll
        for (int it = 0; it < 4; ++it) {
            int r = wr8 + it * 8;
            float4 w4 = *(const float4*)&W[(size_t)(k0 + r) * F + bn + wcq * 4];
            *(float4*)&Ws[r][wcq * 4] = w4;
        }
        __syncthreads();
        #pragma unroll
        for (int kk = 0; kk < BK; ++kk) {
            const float* ap = &As[kk][(ty * 8) ^ (((kk >> 2) & 7) << 3)];
            float4 a0 = *(const float4*)(ap);
            float4 a1 = *(const float4*)(ap + 4);
            const float* wp = &Ws[kk][tx * 8];
            float4 w0 = *(const float4*)(wp);
            float4 w1 = *(const float4*)(wp + 4);
            float a[8] = {a0.x, a0.y, a0.z, a0.w, a1.x, a1.y, a1.z, a1.w};
            float w[8] = {w0.x, w0.y, w0.z, w0.w, w1.x, w1.y, w1.z, w1.w};
            #pragma unroll
            for (int i = 0; i < 8; ++i)
                #pragma unroll
                for (int j = 0; j < 8; ++j)
                    acc[i][j] = fmaf(a[i], w[j], acc[i][j]);
        }
        __syncthreads();
    }
    float4 ba = *(const float4*)&bias[bn + tx * 8];
    float4 bb = *(const float4*)&bias[bn + tx * 8 + 4];
    #pragma unroll
    for (int i = 0; i < 8; ++i) {
        int m = bm + ty * 8 + i;
        if (m < M) {
            float4 v0, v1;
            v0.x = acc[i][0] + ba.x; v0.y = acc[i][1] + ba.y;
            v0.z = acc[i][2] + ba.z; v0.w = acc[i][3] + ba.w;
            v1.x = acc[i][4] + bb.x; v1.y = acc[i][5] + bb.y;
            v1.z = acc[i][6] + bb.z; v1.w = acc[i][7] + bb.w;
            if (do_relu) {
                v0.x = fmaxf(v0.x, 0.f); v0.y = fmaxf(v0.y, 0.f);
                v0.z = fmaxf(v0.z, 0.f); v0.w = fmaxf(v0.w, 0.f);
                v1.x = fmaxf(v1.x, 0.f); v1.y = fmaxf(v1.y, 0.f);
                v1.z = fmaxf(v1.z, 0.f); v1.w = fmaxf(v1.w, 0.f);
            }
            *(float4*)&C[(size_t)m * F + bn + tx * 8]     = v0;
            *(float4*)&C[(size_t)m * F + bn + tx * 8 + 4] = v1;
        }
    }
}

__global__ __launch_bounds__(256, 4) void gemm_bias_act(
    const float* __restrict__ A, const float* __restrict__ W,
    const float* __restrict__ bias, float* __restrict__ C,
    int M, int K, int F, int do_relu)
{
    __shared__ float As[BK][BM];
    __shared__ float Ws[BK][BN];
    gemm_tile(blockIdx.x, blockIdx.y, A, W, bias, C, M, K, F, do_relu, As, Ws);
}

// L1t: 128-wide output, tile128, relaxed bounds so no spill.
__global__ __launch_bounds__(256, 2) void gemm128_bias_act(
    const float* __restrict__ A, const float* __restrict__ W,
    const float* __restrict__ bias, float* __restrict__ C,
    int M, int K, int do_relu)
{
    __shared__ float As[BK][BM];
    __shared__ float Ws[BK][128];
    gemm_tile128(blockIdx.x, 0, A, W, bias, C, M, K, 128, do_relu, As, Ws);
}

// ---------------- fused A: degree+rank || GEMM-L0-s (UNCHANGED, measured 189) --
__global__ __launch_bounds__(256, 4) void fusedA_kernel(
    const float* __restrict__ A, const float* __restrict__ W,
    const float* __restrict__ bias, float* __restrict__ C,
    int M, int K, int F,
    const int* __restrict__ row, const int* __restrict__ col,
    int* __restrict__ deg, int* __restrict__ rank_r, int* __restrict__ rank_c,
    int E, int N, int deg_blocks)
{
    __shared__ float As[BK][BM];
    __shared__ float Ws[BK][BN];
    int g = blockIdx.x / 5;
    int r = blockIdx.x % 5;
    if (r == 0) {
        gemm_tile(g % GXM, g / GXM, A, W, bias, C, M, K, F, 1, As, Ws);
    } else {
        int db = g * 4 + (r - 1);
        if (db < deg_blocks) {
            int e = db * 256 + threadIdx.x;
            if (e < E) {
                rank_r[e] = atomicAdd(&deg[row[e]], 1);
                rank_c[e] = atomicAdd(&deg[N + col[e]], 1);
            }
        }
    }
}

// ---------------- fused B: CSR scatter || L1s (tile128) ----------------------
// %9 map: r==0 -> one of 782 L1s tile128 blocks; r in 1..8 -> edge block
// g*8+(r-1) (782*8 = 6256 >= 6250).
__global__ __launch_bounds__(256, 2) void fusedB_kernel(
    const float* __restrict__ A, const float* __restrict__ W,
    const float* __restrict__ bias, float* __restrict__ C,
    int M, int K,
    const int* __restrict__ row, const int* __restrict__ col,
    const int* __restrict__ rank_r, const int* __restrict__ rank_c,
    const float* __restrict__ outinv, const float* __restrict__ ininv,
    const int* __restrict__ offs, int2* __restrict__ csr,
    int E, int N, int csr_blocks)
{
    __shared__ float As[BK][BM];
    __shared__ float Ws[BK][128];
    int g = blockIdx.x / 9;
    int r = blockIdx.x % 9;
    if (r == 0) {
        gemm_tile128(g, 0, A, W, bias, C, M, K, 128, 1, As, Ws);
    } else {
        int db = g * 8 + (r - 1);
        if (db < csr_blocks) {
            int e = db * 256 + threadIdx.x;
            if (e < E) {
                int rr = row[e], cc = col[e];
                float w = outinv[rr] * ininv[cc];
                int wb = __float_as_int(w);
                csr[offs[rr] + rank_r[e]]     = make_int2(cc, wb);
                csr[offs[N + cc] + rank_c[e]] = make_int2(rr, wb);
            }
        }
    }
}

// ---------------- fused C: L2s (tile64, 782) || L0t (tile128, 782) -----------
__global__ __launch_bounds__(256, 2) void fusedC_kernel(
    const float* __restrict__ A0, const float* __restrict__ W0,
    const float* __restrict__ b0, float* __restrict__ C0, int K0,
    const float* __restrict__ A1, const float* __restrict__ W1,
    const float* __restrict__ b1, float* __restrict__ C1, int K1,
    int M)
{
    __shared__ float As[BK][BM];
    __shared__ float Ws[BK][128];
    int g = blockIdx.x >> 1;
    if ((blockIdx.x & 1) == 0) {
        gemm_tile(g, 0, A0, W0, b0, C0, M, K0, DIM_OUT, 0, As, (float(*)[BN])Ws);
    } else {
        gemm_tile128(g, 0, A1, W1, b1, C1, M, K1, 128, 1, As, Ws);
    }
}

// ---------------- zero helper ----------------
__global__ void zero_int_kernel(int* __restrict__ p, int n) {
    int i = blockIdx.x * blockDim.x + threadIdx.x;
    if (i < n) p[i] = 0;
}

// ---------------- segment-base allocation + inv ------------------------------
// Segment ORDER in CSR memory is arbitrary: conv reads offs[wid]/deg[wid]
// directly; within-segment order stays = rank order -> bitwise-identical.
__global__ __launch_bounds__(256) void alloc_inv_kernel(
    const int* __restrict__ deg, int* __restrict__ offs, int* __restrict__ ctr,
    float* __restrict__ outinv, float* __restrict__ ininv,
    float* __restrict__ wself, int N)
{
    int i = blockIdx.x * 256 + threadIdx.x;
    int twoN = 2 * N;
    int lane = threadIdx.x & 63;
    int d = (i < twoN) ? deg[i] : 0;
    int incl = d;
    #pragma unroll
    for (int off = 1; off < 64; off <<= 1) {
        int v = __shfl_up(incl, off, 64);
        if (lane >= off) incl += v;
    }
    int wavetotal = __shfl(incl, 63, 64);
    int base = 0;
    if (lane == 63) base = atomicAdd(ctr, wavetotal);
    base = __shfl(base, 63, 64);
    if (i < twoN) offs[i] = base + incl - d;   // exclusive within wave
    if (i < N) {
        float oi = rsqrtf((float)(deg[i] + 1));       // +1 self-loop
        float ii = rsqrtf((float)(deg[N + i] + 1));
        outinv[i] = oi;
        ininv[i] = ii;
        wself[i] = oi * ii;
    }
}

// ---------------- fused conv round (UNCHANGED) --------------------------------
#define DEPTH 8
__global__ __launch_bounds__(256) void conv_gather_kernel(
    const int* __restrict__ offs, const int* __restrict__ deg,
    const int2* __restrict__ csr, const float* __restrict__ wself,
    const float* __restrict__ s_old, const float* __restrict__ t_old,
    float* __restrict__ s_new, float* __restrict__ t_new,
    const float* __restrict__ conv_w, int k, int N)
{
    int wid = (int)((blockIdx.x * blockDim.x + threadIdx.x) >> 6);
    int lane = threadIdx.x & 63;
    if (wid >= 2 * N) return;
    int side = (wid >= N) ? 1 : 0;
    int n = side ? wid - N : wid;
    const float* other = side ? s_old : t_old;
    const float* self  = side ? t_old : s_old;
    float* out         = side ? t_new : s_new;
    float coef = conv_w[2 * k + side];

    int start = offs[wid];
    int d     = deg[wid];
    start = __builtin_amdgcn_readfirstlane(start);
    d     = __builtin_amdgcn_readfirstlane(d);
    int end = start + d;

    const unsigned long long* csr8 = (const unsigned long long*)csr;

    float acc[DEPTH];
    acc[0] = wself[n] * other[(size_t)n * 64 + lane];
    #pragma unroll
    for (int u = 1; u < DEPTH; ++u) acc[u] = 0.f;

    for (int p = start; p < end; p += DEPTH) {
        unsigned long long e[DEPTH];
        #pragma unroll
        for (int u = 0; u < DEPTH; ++u) {
            int q = p + u;
            q = (q < end) ? q : (end - 1);        // clamp: harmless cached re-read
            e[u] = __builtin_nontemporal_load(&csr8[q]);
        }
        #pragma unroll
        for (int u = 0; u < DEPTH; ++u) {
            float f = other[(size_t)(unsigned int)e[u] * 64 + lane];
            float w = (p + u < end) ? __int_as_float((int)(e[u] >> 32)) : 0.f;
            acc[u] = fmaf(w, f, acc[u]);
        }
    }

    #pragma unroll
    for (int s = DEPTH / 2; s >= 1; s >>= 1)
        #pragma unroll
        for (int u = 0; u < s; ++u) acc[u] += acc[u + s];

    size_t off = (size_t)n * 64 + lane;
    out[off] = fmaf(coef, acc[0], self[off]);
}

extern "C" void kernel_launch(void* const* d_in, const int* in_sizes, int n_in,
                              void* d_out, int out_size, void* d_ws, size_t ws_size,
                              hipStream_t stream) {
    const int N = N_NODES;
    const int E = N_EDGES;

    const float* s_in  = (const float*)d_in[0];
    const float* t_in  = (const float*)d_in[1];
    const int*   ei    = (const int*)d_in[2];
    const int*   row   = ei;
    const int*   col   = ei + E;
    const float* Ws0 = (const float*)d_in[3];
    const float* bs0 = (const float*)d_in[4];
    const float* Wt0 = (const float*)d_in[5];
    const float* bt0 = (const float*)d_in[6];
    const float* Ws1 = (const float*)d_in[7];
    const float* bs1 = (const float*)d_in[8];
    const float* Wt1 = (const float*)d_in[9];
    const float* bt1 = (const float*)d_in[10];
    const float* Ws2 = (const float*)d_in[11];
    const float* bs2 = (const float*)d_in[12];
    const float* Wt2 = (const float*)d_in[13];
    const float* bt2 = (const float*)d_in[14];
    const float* conv_w = (const float*)d_in[15];

    float* out_s = (float*)d_out;
    float* out_t = (float*)d_out + (size_t)N * DIM_OUT;

    // workspace layout (4-byte units)
    float* ws = (float*)d_ws;
    float* H1 = ws;                                   // N*128 (later S1/T1)
    float* H2 = ws + (size_t)N * DIM_HID;             // N*128
    float* S0 = ws + 2 * (size_t)N * DIM_HID;         // N*64
    float* T0 = S0 + (size_t)N * DIM_OUT;             // N*64
    float* S1 = H1;                                   // alias (free after L2t)
    float* T1 = H1 + (size_t)N * DIM_OUT;
    int2*  CSR    = (int2*)(T0 + (size_t)N * DIM_OUT);   // 2E int2
    float* OUTINV = (float*)(CSR + 2 * (size_t)E);       // N
    float* ININV  = OUTINV + N;                          // N
    float* WSELF  = ININV + N;                           // N
    int*   DEG    = (int*)(WSELF + N);                   // 2N
    int*   CTR    = DEG + 2 * N;                         // 1 (segment-base counter)
    int*   OFFS   = CTR + 1;                             // 2N (segment starts)
    // RANK arrays alias S0/T0: produced in fusedA, consumed in fusedB, dead
    // before fusedC writes S0.
    int*   RANKR  = (int*)S0;                            // E
    int*   RANKC  = RANKR + E;                           // E

    const int twoN = 2 * N;
    const int edge_blocks = (E + 255) / 256;             // 6250
    const int gemm_blocks = GXM * (DIM_HID / BN);        // 1564 (tile64 L0s)
    const int fusedA_blocks = gemm_blocks * 5;           // 1:4 interleave

    // ---- zero degree counters + segment-base counter ----
    zero_int_kernel<<<(twoN + 1 + 255) / 256, 256, 0, stream>>>(DEG, twoN + 1);

    // ---- fusedA: degree+rank || GEMM-L0-s(s_in->H2), tile64, unchanged ----
    fusedA_kernel<<<fusedA_blocks, 256, 0, stream>>>(
        s_in, Ws0, bs0, H2, N, DIM_IN, DIM_HID,
        row, col, DEG, RANKR, RANKC, E, N, edge_blocks);

    // ---- segment-base alloc + inv ----
    alloc_inv_kernel<<<(twoN + 255) / 256, 256, 0, stream>>>(
        DEG, OFFS, CTR, OUTINV, ININV, WSELF, N);

    // ---- fusedB: CSR scatter || L1s(H2->H1), tile128 ----
    fusedB_kernel<<<GXM * 9, 256, 0, stream>>>(
        H2, Ws1, bs1, H1, N, DIM_HID,
        row, col, RANKR, RANKC, OUTINV, ININV, OFFS, CSR, E, N, edge_blocks);

    // ---- fusedC: L2s(H1->S0, tile64) || L0t(t_in->H2, tile128) ----
    fusedC_kernel<<<GXM * 2, 256, 0, stream>>>(
        H1, Ws2, bs2, S0, DIM_HID,
        t_in, Wt0, bt0, H2, DIM_IN,
        N);

    // ---- L1t(H2->H1, tile128) then L2t(H1->T0, tile64) ----
    gemm128_bias_act<<<GXM, 256, 0, stream>>>(H2, Wt1, bt1, H1, N, DIM_HID, 1);
    dim3 blk(256);
    dim3 g3(GXM, 1);
    gemm_bias_act<<<g3, blk, 0, stream>>>(H1, Wt2, bt2, T0, N, DIM_HID, DIM_OUT, 0);

    // ---- 3 conv rounds, wave-per-node gather ----
    const int gather_blocks = (twoN * 64 + 255) / 256;   // 4 waves/block
    conv_gather_kernel<<<gather_blocks, 256, 0, stream>>>(OFFS, DEG, CSR, WSELF, S0, T0, S1, T1, conv_w, 0, N);
    conv_gather_kernel<<<gather_blocks, 256, 0, stream>>>(OFFS, DEG, CSR, WSELF, S1, T1, S0, T0, conv_w, 1, N);
    conv_gather_kernel<<<gather_blocks, 256, 0, stream>>>(OFFS, DEG, CSR, WSELF, S0, T0, out_s, out_t, conv_w, 2, N);
}

// Round 9
// 1042.162 us; speedup vs baseline: 1.1013x; 1.1013x over previous
//
#include <hip/hip_runtime.h>

#define N_NODES 100000
#define N_EDGES 1600000
#define DIM_IN  256
#define DIM_HID 128
#define DIM_OUT 64

// ---------------- GEMM tile: C = act(A @ W + bias) ----------------
// 128x64 tile, BK=32, 256 threads, 8x4 acc/thread (52 VGPR, fits (256,4)).
// tile128 closed: r5 spilled under (256,4); r7 at (256,2) lost occupancy
// (12%) + 4.7x bank conflicts. tile64 is the operating point.
#define BM 128
#define BN 64
#define BK 32
#define GXM ((N_NODES + BM - 1) / BM)   // 782 M-tiles

__device__ __forceinline__ void gemm_tile(
    int bx, int by,
    const float* __restrict__ A, const float* __restrict__ W,
    const float* __restrict__ bias, float* __restrict__ C,
    int M, int K, int F, int do_relu,
    float (*As)[BM], float (*Ws)[BN])
{
    const int tid = threadIdx.x;
    const int tx = tid & 15;        // n: 4 cols each
    const int ty = tid >> 4;        // m: 8 rows each
    const int bm = bx * BM;
    const int bn = by * BN;

    const int am  = tid >> 3;       // A staging: row 0..31 (+32*it)
    const int akq = tid & 7;        // A staging: float4 index within 32-k row
    const int wr  = tid >> 4;       // W staging: row 0..15 (+16*it)
    const int wcq = tid & 15;       // W staging: float4 col

    float acc[8][4] = {};

    for (int k0 = 0; k0 < K; k0 += BK) {
        #pragma unroll
        for (int it = 0; it < 4; ++it) {
            int m = am + it * 32;
            int gm = bm + m;
            float4 a4 = make_float4(0.f, 0.f, 0.f, 0.f);
            if (gm < M)
                a4 = *(const float4*)&A[(size_t)gm * K + k0 + akq * 4];
            int msw = m ^ (akq << 3);
            As[akq * 4 + 0][msw] = a4.x;
            As[akq * 4 + 1][msw] = a4.y;
            As[akq * 4 + 2][msw] = a4.z;
            As[akq * 4 + 3][msw] = a4.w;
        }
        #pragma unroll
        for (int it = 0; it < 2; ++it) {
            int r = wr + it * 16;
            float4 w4 = *(const float4*)&W[(size_t)(k0 + r) * F + bn + wcq * 4];
            *(float4*)&Ws[r][wcq * 4] = w4;
        }
        __syncthreads();
        #pragma unroll
        for (int kk = 0; kk < BK; ++kk) {
            const float* ap = &As[kk][(ty * 8) ^ (((kk >> 2) & 7) << 3)];
            float4 a0 = *(const float4*)(ap);
            float4 a1 = *(const float4*)(ap + 4);
            float4 w4 = *(const float4*)&Ws[kk][tx * 4];
            float a[8] = {a0.x, a0.y, a0.z, a0.w, a1.x, a1.y, a1.z, a1.w};
            float w[4] = {w4.x, w4.y, w4.z, w4.w};
            #pragma unroll
            for (int i = 0; i < 8; ++i)
                #pragma unroll
                for (int j = 0; j < 4; ++j)
                    acc[i][j] = fmaf(a[i], w[j], acc[i][j]);
        }
        __syncthreads();
    }
    float4 b4 = *(const float4*)&bias[bn + tx * 4];
    #pragma unroll
    for (int i = 0; i < 8; ++i) {
        int m = bm + ty * 8 + i;
        if (m < M) {
            float4 v;
            v.x = acc[i][0] + b4.x;
            v.y = acc[i][1] + b4.y;
            v.z = acc[i][2] + b4.z;
            v.w = acc[i][3] + b4.w;
            if (do_relu) {
                v.x = fmaxf(v.x, 0.f); v.y = fmaxf(v.y, 0.f);
                v.z = fmaxf(v.z, 0.f); v.w = fmaxf(v.w, 0.f);
            }
            *(float4*)&C[(size_t)m * F + bn + tx * 4] = v;
        }
    }
}

__global__ __launch_bounds__(256, 4) void gemm_bias_act(
    const float* __restrict__ A, const float* __restrict__ W,
    const float* __restrict__ bias, float* __restrict__ C,
    int M, int K, int F, int do_relu)
{
    __shared__ float As[BK][BM];
    __shared__ float Ws[BK][BN];
    gemm_tile(blockIdx.x, blockIdx.y, A, W, bias, C, M, K, F, do_relu, As, Ws);
}

// ---------------- fused A: degree+rank (coherence-bound) || GEMM-L0-s ----------
// block mapping interleaves 1 gemm : 4 degree so both cohorts are co-resident.
// deg layout: [0,N) = outdeg (row), [N,2N) = indeg (col)
__global__ __launch_bounds__(256, 4) void fusedA_kernel(
    const float* __restrict__ A, const float* __restrict__ W,
    const float* __restrict__ bias, float* __restrict__ C,
    int M, int K, int F,
    const int* __restrict__ row, const int* __restrict__ col,
    int* __restrict__ deg, int* __restrict__ rank_r, int* __restrict__ rank_c,
    int E, int N, int deg_blocks)
{
    __shared__ float As[BK][BM];
    __shared__ float Ws[BK][BN];
    int g = blockIdx.x / 5;
    int r = blockIdx.x % 5;
    if (r == 0) {
        gemm_tile(g % GXM, g / GXM, A, W, bias, C, M, K, F, 1, As, Ws);
    } else {
        int db = g * 4 + (r - 1);
        if (db < deg_blocks) {
            int e = db * 256 + threadIdx.x;
            if (e < E) {
                rank_r[e] = atomicAdd(&deg[row[e]], 1);
                rank_c[e] = atomicAdd(&deg[N + col[e]], 1);
            }
        }
    }
}

// ---------------- fused B: CSR scatter (fire-and-forget) || GEMM-L1-s ----------
__global__ __launch_bounds__(256, 4) void fusedB_kernel(
    const float* __restrict__ A, const float* __restrict__ W,
    const float* __restrict__ bias, float* __restrict__ C,
    int M, int K, int F,
    const int* __restrict__ row, const int* __restrict__ col,
    const int* __restrict__ rank_r, const int* __restrict__ rank_c,
    const float* __restrict__ outinv, const float* __restrict__ ininv,
    const int* __restrict__ offs, int2* __restrict__ csr,
    int E, int N, int csr_blocks)
{
    __shared__ float As[BK][BM];
    __shared__ float Ws[BK][BN];
    int g = blockIdx.x / 5;
    int r = blockIdx.x % 5;
    if (r == 0) {
        gemm_tile(g % GXM, g / GXM, A, W, bias, C, M, K, F, 1, As, Ws);
    } else {
        int db = g * 4 + (r - 1);
        if (db < csr_blocks) {
            int e = db * 256 + threadIdx.x;
            if (e < E) {
                int rr = row[e], cc = col[e];
                float w = outinv[rr] * ininv[cc];
                int wb = __float_as_int(w);
                csr[offs[rr] + rank_r[e]]     = make_int2(cc, wb);
                csr[offs[N + cc] + rank_c[e]] = make_int2(rr, wb);
            }
        }
    }
}

// ---------------- fused C: GEMM-L2-s (782 tiles) || GEMM-L0-t (1564 tiles), %3 --
__global__ __launch_bounds__(256, 4) void fusedC_kernel(
    const float* __restrict__ A0, const float* __restrict__ W0,
    const float* __restrict__ b0, float* __restrict__ C0, int K0, int F0, int relu0,
    const float* __restrict__ A1, const float* __restrict__ W1,
    const float* __restrict__ b1, float* __restrict__ C1, int K1, int F1, int relu1,
    int M)
{
    __shared__ float As[BK][BM];
    __shared__ float Ws[BK][BN];
    int g = blockIdx.x / 3;
    int r = blockIdx.x % 3;
    if (r == 0) {
        gemm_tile(g % GXM, g / GXM, A0, W0, b0, C0, M, K0, F0, relu0, As, Ws);
    } else {
        int idx = g * 2 + (r - 1);
        gemm_tile(idx % GXM, idx / GXM, A1, W1, b1, C1, M, K1, F1, relu1, As, Ws);
    }
}

// ---------------- degree helpers ----------------
__global__ void zero_int_kernel(int* __restrict__ p, int n) {
    int i = blockIdx.x * blockDim.x + threadIdx.x;
    if (i < n) p[i] = 0;
}

// ---------------- scan (blocks 0..sb-1) fused with inv (blocks sb..) ----------
__global__ __launch_bounds__(256) void scan_inv_kernel(
    const int* __restrict__ in, int* __restrict__ out,
    int* __restrict__ blocksums, int n2,          // scan over n2 = 2N
    float* __restrict__ outinv, float* __restrict__ ininv,
    float* __restrict__ wself, int n, int scan_blocks)
{
    int tid = threadIdx.x;
    if ((int)blockIdx.x < scan_blocks) {
        __shared__ int tmp[256];
        int gid = blockIdx.x * 256 + tid;
        int v = (gid < n2) ? in[gid] : 0;
        tmp[tid] = v;
        __syncthreads();
        for (int off = 1; off < 256; off <<= 1) {
            int t = (tid >= off) ? tmp[tid - off] : 0;
            __syncthreads();
            tmp[tid] += t;
            __syncthreads();
        }
        if (gid < n2) out[gid] = tmp[tid] - v;   // exclusive
        if (tid == 255) blocksums[blockIdx.x] = tmp[255];
    } else {
        int i = ((int)blockIdx.x - scan_blocks) * 256 + tid;
        if (i < n) {
            float oi = rsqrtf((float)(in[i] + 1));       // +1 self-loop
            float ii = rsqrtf((float)(in[n + i] + 1));
            outinv[i] = oi;
            ininv[i] = ii;
            wself[i] = oi * ii;
        }
    }
}

__global__ __launch_bounds__(1024) void scan_sums_kernel(int* __restrict__ blocksums, int nb) {
    __shared__ int tmp[1024];
    int tid = threadIdx.x;
    int v = (tid < nb) ? blocksums[tid] : 0;
    tmp[tid] = v;
    __syncthreads();
    for (int off = 1; off < 1024; off <<= 1) {
        int t = (tid >= off) ? tmp[tid - off] : 0;
        __syncthreads();
        tmp[tid] += t;
        __syncthreads();
    }
    if (tid < nb) blocksums[tid] = tmp[tid] - v;  // exclusive block offsets
}

__global__ void add_offsets_kernel(int* __restrict__ out, const int* __restrict__ blocksums, int n) {
    int gid = blockIdx.x * 256 + threadIdx.x;
    if (gid < n) out[gid] += blocksums[blockIdx.x];
}

// ---------------- fused conv round: gather + self-loop + residual ----------------
// wave (64 lanes) per output node; lanes = feature dim.
// 8-deep software pipeline (D16 wastes ~2x clamped NT-load slots at mean deg 16).
#define DEPTH 8
__global__ __launch_bounds__(256) void conv_gather_kernel(
    const int* __restrict__ offs, const int* __restrict__ deg,
    const int2* __restrict__ csr, const float* __restrict__ wself,
    const float* __restrict__ s_old, const float* __restrict__ t_old,
    float* __restrict__ s_new, float* __restrict__ t_new,
    const float* __restrict__ conv_w, int k, int N)
{
    int wid = (int)((blockIdx.x * blockDim.x + threadIdx.x) >> 6);
    int lane = threadIdx.x & 63;
    if (wid >= 2 * N) return;
    int side = (wid >= N) ? 1 : 0;
    int n = side ? wid - N : wid;
    const float* other = side ? s_old : t_old;
    const float* self  = side ? t_old : s_old;
    float* out         = side ? t_new : s_new;
    float coef = conv_w[2 * k + side];

    int start = offs[wid];
    int d     = deg[wid];
    start = __builtin_amdgcn_readfirstlane(start);
    d     = __builtin_amdgcn_readfirstlane(d);
    int end = start + d;

    const unsigned long long* csr8 = (const unsigned long long*)csr;

    float acc[DEPTH];
    acc[0] = wself[n] * other[(size_t)n * 64 + lane];
    #pragma unroll
    for (int u = 1; u < DEPTH; ++u) acc[u] = 0.f;

    for (int p = start; p < end; p += DEPTH) {
        unsigned long long e[DEPTH];
        #pragma unroll
        for (int u = 0; u < DEPTH; ++u) {
            int q = p + u;
            q = (q < end) ? q : (end - 1);        // clamp: harmless cached re-read
            e[u] = __builtin_nontemporal_load(&csr8[q]);
        }
        #pragma unroll
        for (int u = 0; u < DEPTH; ++u) {
            float f = other[(size_t)(unsigned int)e[u] * 64 + lane];
            float w = (p + u < end) ? __int_as_float((int)(e[u] >> 32)) : 0.f;
            acc[u] = fmaf(w, f, acc[u]);
        }
    }

    #pragma unroll
    for (int s = DEPTH / 2; s >= 1; s >>= 1)
        #pragma unroll
        for (int u = 0; u < s; ++u) acc[u] += acc[u + s];

    size_t off = (size_t)n * 64 + lane;
    out[off] = fmaf(coef, acc[0], self[off]);
}

extern "C" void kernel_launch(void* const* d_in, const int* in_sizes, int n_in,
                              void* d_out, int out_size, void* d_ws, size_t ws_size,
                              hipStream_t stream) {
    const int N = N_NODES;
    const int E = N_EDGES;

    const float* s_in  = (const float*)d_in[0];
    const float* t_in  = (const float*)d_in[1];
    const int*   ei    = (const int*)d_in[2];
    const int*   row   = ei;
    const int*   col   = ei + E;
    const float* Ws0 = (const float*)d_in[3];
    const float* bs0 = (const float*)d_in[4];
    const float* Wt0 = (const float*)d_in[5];
    const float* bt0 = (const float*)d_in[6];
    const float* Ws1 = (const float*)d_in[7];
    const float* bs1 = (const float*)d_in[8];
    const float* Wt1 = (const float*)d_in[9];
    const float* bt1 = (const float*)d_in[10];
    const float* Ws2 = (const float*)d_in[11];
    const float* bs2 = (const float*)d_in[12];
    const float* Wt2 = (const float*)d_in[13];
    const float* bt2 = (const float*)d_in[14];
    const float* conv_w = (const float*)d_in[15];

    float* out_s = (float*)d_out;
    float* out_t = (float*)d_out + (size_t)N * DIM_OUT;

    // workspace layout (4-byte units)
    float* ws = (float*)d_ws;
    float* H1 = ws;                                   // N*128 (later S1/T1)
    float* H2 = ws + (size_t)N * DIM_HID;             // N*128
    float* S0 = ws + 2 * (size_t)N * DIM_HID;         // N*64
    float* T0 = S0 + (size_t)N * DIM_OUT;             // N*64
    float* S1 = H1;                                   // alias (free after L2t)
    float* T1 = H1 + (size_t)N * DIM_OUT;
    int2*  CSR    = (int2*)(T0 + (size_t)N * DIM_OUT);   // 2E int2
    float* OUTINV = (float*)(CSR + 2 * (size_t)E);       // N
    float* ININV  = OUTINV + N;                          // N
    float* WSELF  = ININV + N;                           // N
    int*   DEG    = (int*)(WSELF + N);                   // 2N
    int*   OFFS   = DEG + 2 * N;                         // 2N (segment starts)
    int*   BSUMS  = OFFS + 2 * N;                        // ~1024
    // RANK arrays alias S0/T0: produced in fusedA, consumed in fusedB, dead
    // before fusedC writes S0.
    int*   RANKR  = (int*)S0;                            // E
    int*   RANKC  = RANKR + E;                           // E

    const int twoN = 2 * N;
    const int scan_blocks = (twoN + 255) / 256;          // 782
    const int inv_blocks  = (N + 255) / 256;             // 391
    const int edge_blocks = (E + 255) / 256;             // 6250
    const int gemm_blocks = GXM * (DIM_HID / BN);        // 1564
    const int fused_blocks = gemm_blocks * 5;            // 1:4 interleave

    // ---- zero degree counters ----
    zero_int_kernel<<<(twoN + 255) / 256, 256, 0, stream>>>(DEG, twoN);

    // ---- fusedA: degree+rank || GEMM-L0-s(s_in->H2) ----
    fusedA_kernel<<<fused_blocks, 256, 0, stream>>>(
        s_in, Ws0, bs0, H2, N, DIM_IN, DIM_HID,
        row, col, DEG, RANKR, RANKC, E, N, edge_blocks);

    // ---- scan of DEG -> OFFS (block-local) fused with inv ----
    scan_inv_kernel<<<scan_blocks + inv_blocks, 256, 0, stream>>>(
        DEG, OFFS, BSUMS, twoN, OUTINV, ININV, WSELF, N, scan_blocks);
    scan_sums_kernel<<<1, 1024, 0, stream>>>(BSUMS, scan_blocks);
    add_offsets_kernel<<<scan_blocks, 256, 0, stream>>>(OFFS, BSUMS, twoN);

    // ---- fusedB: CSR scatter || GEMM-L1-s(H2->H1) ----
    fusedB_kernel<<<fused_blocks, 256, 0, stream>>>(
        H2, Ws1, bs1, H1, N, DIM_HID, DIM_HID,
        row, col, RANKR, RANKC, OUTINV, ININV, OFFS, CSR, E, N, edge_blocks);

    // ---- fusedC: GEMM-L2-s(H1->S0) || GEMM-L0-t(t_in->H2) ----
    fusedC_kernel<<<GXM * 3, 256, 0, stream>>>(
        H1, Ws2, bs2, S0, DIM_HID, DIM_OUT, 0,
        t_in, Wt0, bt0, H2, DIM_IN, DIM_HID, 1,
        N);

    // ---- remaining t-path MLPs ----
    dim3 blk(256);
    dim3 g1(GXM, DIM_HID / BN);
    dim3 g3(GXM, DIM_OUT / BN);
    gemm_bias_act<<<g1, blk, 0, stream>>>(H2, Wt1, bt1, H1, N, DIM_HID, DIM_HID, 1);
    gemm_bias_act<<<g3, blk, 0, stream>>>(H1, Wt2, bt2, T0, N, DIM_HID, DIM_OUT, 0);

    // ---- 3 conv rounds, wave-per-node gather ----
    const int gather_blocks = (twoN * 64 + 255) / 256;   // 4 waves/block
    conv_gather_kernel<<<gather_blocks, 256, 0, stream>>>(OFFS, DEG, CSR, WSELF, S0, T0, S1, T1, conv_w, 0, N);
    conv_gather_kernel<<<gather_blocks, 256, 0, stream>>>(OFFS, DEG, CSR, WSELF, S1, T1, S0, T0, conv_w, 1, N);
    conv_gather_kernel<<<gather_blocks, 256, 0, stream>>>(OFFS, DEG, CSR, WSELF, S0, T0, out_s, out_t, conv_w, 2, N);
}